// Round 2
// baseline (433.228 us; speedup 1.0000x reference)
//
#include <hip/hip_runtime.h>

#define GRID 64
#define N_VOX (GRID * GRID * GRID)   // 262144
#define NCH 64
#define NCHUNK 256                   // scan chunks (1024 counts each)

// ============================================================================
// Pipeline: hist(+rank, 8pts/thr) -> scan(single kernel, decoupled lookback)
//           -> scatter(no atomics, 8pts/thr) -> gather(LDS idx, exact loads)
// ============================================================================

typedef float f32x4 __attribute__((ext_vector_type(4)));
typedef int   i32x4 __attribute__((ext_vector_type(4)));

__device__ __forceinline__ int vox_of(int x, int y, int z) {
    return ((x >> 2) << 12) | ((y >> 2) << 6) | (z >> 2);
}

__device__ __forceinline__ float4 max4(float4 a, float4 b) {
    float4 r;
    r.x = fmaxf(a.x, b.x); r.y = fmaxf(a.y, b.y);
    r.z = fmaxf(a.z, b.z); r.w = fmaxf(a.w, b.w);
    return r;
}

// non-temporal helpers (read-once / write-once data: keep it out of L2)
__device__ __forceinline__ float4 ntload4(const float4* p) {
    f32x4 v = __builtin_nontemporal_load((const f32x4*)p);
    return make_float4(v[0], v[1], v[2], v[3]);
}
__device__ __forceinline__ void ntstore4(float4* p, float4 v) {
    f32x4 t; t[0] = v.x; t[1] = v.y; t[2] = v.z; t[3] = v.w;
    __builtin_nontemporal_store(t, (f32x4*)p);
}
__device__ __forceinline__ int4 ntload_i4(const int4* p) {
    i32x4 v = __builtin_nontemporal_load((const i32x4*)p);
    return make_int4(v[0], v[1], v[2], v[3]);
}

// ---- k1: voxel id + in-voxel rank per point + histogram, 8 pts/thread ---
__global__ void k_hist(const int* __restrict__ verts, int* __restrict__ vox,
                       int* __restrict__ rank, int* __restrict__ counts, int n) {
    int t  = blockIdx.x * blockDim.x + threadIdx.x;
    int p0 = t * 8;
    if (p0 >= n) return;

    if (p0 + 8 <= n) {
        const int4* v4 = (const int4*)verts;
        int4 a = ntload_i4(&v4[6 * t + 0]);
        int4 b = ntload_i4(&v4[6 * t + 1]);
        int4 c = ntload_i4(&v4[6 * t + 2]);
        int4 d = ntload_i4(&v4[6 * t + 3]);
        int4 e = ntload_i4(&v4[6 * t + 4]);
        int4 f = ntload_i4(&v4[6 * t + 5]);
        int w0 = vox_of(a.x, a.y, a.z);
        int w1 = vox_of(a.w, b.x, b.y);
        int w2 = vox_of(b.z, b.w, c.x);
        int w3 = vox_of(c.y, c.z, c.w);
        int w4 = vox_of(d.x, d.y, d.z);
        int w5 = vox_of(d.w, e.x, e.y);
        int w6 = vox_of(e.z, e.w, f.x);
        int w7 = vox_of(f.y, f.z, f.w);
        ((int4*)vox)[2 * t + 0] = make_int4(w0, w1, w2, w3);
        ((int4*)vox)[2 * t + 1] = make_int4(w4, w5, w6, w7);
        int r0 = atomicAdd(&counts[w0], 1);
        int r1 = atomicAdd(&counts[w1], 1);
        int r2 = atomicAdd(&counts[w2], 1);
        int r3 = atomicAdd(&counts[w3], 1);
        int r4 = atomicAdd(&counts[w4], 1);
        int r5 = atomicAdd(&counts[w5], 1);
        int r6 = atomicAdd(&counts[w6], 1);
        int r7 = atomicAdd(&counts[w7], 1);
        ((int4*)rank)[2 * t + 0] = make_int4(r0, r1, r2, r3);
        ((int4*)rank)[2 * t + 1] = make_int4(r4, r5, r6, r7);
    } else {
        for (int p = p0; p < n; p++) {
            int w = vox_of(verts[3 * p], verts[3 * p + 1], verts[3 * p + 2]);
            vox[p]  = w;
            rank[p] = atomicAdd(&counts[w], 1);
        }
    }
}

// ---- k2: full exclusive scan in ONE kernel (decoupled lookback) --------
// 256 blocks x 256 threads; block (by ticket) b scans counts[b*1024 .. +1024)
// state[b]: hi32 = flag (0 none, 1 aggregate, 2 inclusive-prefix), lo32 = value
__global__ void __launch_bounds__(256)
k_scan(const int* __restrict__ counts, int* __restrict__ gstart,
       unsigned long long* __restrict__ state, int* __restrict__ ticket) {
    __shared__ int s_ticket;
    __shared__ int wbase[4];
    __shared__ int s_base;

    if (threadIdx.x == 0) s_ticket = atomicAdd(ticket, 1);
    __syncthreads();
    const int b    = s_ticket;          // chunk id, in scheduling order
    const int t    = threadIdx.x;
    const int lane = t & 63;
    const int wid  = t >> 6;

    int4 c = ((const int4*)counts)[b * 256 + t];
    int s = c.x + c.y + c.z + c.w;

    int incl = s;
    #pragma unroll
    for (int off = 1; off < 64; off <<= 1) {
        int u = __shfl_up(incl, off);
        if (lane >= off) incl += u;
    }
    if (lane == 63) wbase[wid] = incl;
    __syncthreads();

    if (wid == 0) {
        int agg = wbase[0] + wbase[1] + wbase[2] + wbase[3];
        if (lane == 0) {
            __hip_atomic_store(&state[b], (1ULL << 32) | (unsigned)agg,
                               __ATOMIC_RELEASE, __HIP_MEMORY_SCOPE_AGENT);
        }
        // wave-parallel lookback: 64 predecessors per round
        int excl = 0;
        int p_hi = b - 1;
        while (p_hi >= 0) {
            int p = p_hi - lane;
            unsigned long long v;
            do {
                v = (p >= 0)
                  ? __hip_atomic_load(&state[p], __ATOMIC_ACQUIRE,
                                      __HIP_MEMORY_SCOPE_AGENT)
                  : (2ULL << 32);               // virtual terminator, value 0
            } while (__any((int)((v >> 32) == 0)));
            unsigned long long m = __ballot((int)((v >> 32) == 2));
            int cut = m ? (__ffsll((long long)m) - 1) : 64;
            int contrib = (lane <= cut) ? (int)(unsigned)v : 0;
            #pragma unroll
            for (int o = 32; o; o >>= 1) contrib += __shfl_down(contrib, o);
            excl += __shfl(contrib, 0);
            if (m) break;
            p_hi -= 64;
        }
        if (lane == 0) {
            int agg2 = wbase[0] + wbase[1] + wbase[2] + wbase[3];
            __hip_atomic_store(&state[b], (2ULL << 32) | (unsigned)(excl + agg2),
                               __ATOMIC_RELEASE, __HIP_MEMORY_SCOPE_AGENT);
            s_base = excl;
            if (b == NCHUNK - 1) gstart[N_VOX] = excl + agg2;   // sentinel
        }
    }
    __syncthreads();

    int wexcl = 0;
    for (int i = 0; i < wid; i++) wexcl += wbase[i];
    int base = s_base + wexcl + (incl - s);
    int4 g;
    g.x = base;
    g.y = base + c.x;
    g.z = base + c.x + c.y;
    g.w = base + c.x + c.y + c.z;
    ((int4*)gstart)[b * 256 + t] = g;
}

// ---- k3: scatter point indices — NO atomics, 8 pts/thread --------------
__global__ void k_scatter_idx(const int* __restrict__ vox,
                              const int* __restrict__ rank,
                              const int* __restrict__ gstart,
                              int* __restrict__ sorted_idx, int n) {
    int t  = blockIdx.x * blockDim.x + threadIdx.x;
    int p0 = t * 8;
    if (p0 >= n) return;

    if (p0 + 8 <= n) {
        int4 w0 = ((const int4*)vox)[2 * t + 0];
        int4 w1 = ((const int4*)vox)[2 * t + 1];
        int4 r0 = ((const int4*)rank)[2 * t + 0];
        int4 r1 = ((const int4*)rank)[2 * t + 1];
        sorted_idx[gstart[w0.x] + r0.x] = p0 + 0;
        sorted_idx[gstart[w0.y] + r0.y] = p0 + 1;
        sorted_idx[gstart[w0.z] + r0.z] = p0 + 2;
        sorted_idx[gstart[w0.w] + r0.w] = p0 + 3;
        sorted_idx[gstart[w1.x] + r1.x] = p0 + 4;
        sorted_idx[gstart[w1.y] + r1.y] = p0 + 5;
        sorted_idx[gstart[w1.z] + r1.z] = p0 + 6;
        sorted_idx[gstart[w1.w] + r1.w] = p0 + 7;
    } else {
        for (int p = p0; p < n; p++)
            sorted_idx[gstart[vox[p]] + rank[p]] = p;
    }
}

// ---- k4: gather max — 16 voxels/block, LDS idx, EXACT load count -------
#define VPB 16          // voxels per 256-thread block
#define IDX_CAP 2048    // LDS slots for the block's sorted_idx slice

__global__ void __launch_bounds__(256)
k_gather(const int* __restrict__ sorted_idx,
         const int* __restrict__ gstart,
         const float4* __restrict__ feats4,   // [N, 16] float4
         float4* __restrict__ out4) {         // [N_VOX, 16] float4
    __shared__ int sst[VPB + 1];
    __shared__ int sidx[IDX_CAP];

    int vox0 = blockIdx.x * VPB;
    if (threadIdx.x < VPB + 1) sst[threadIdx.x] = gstart[vox0 + threadIdx.x];
    __syncthreads();

    int bstart = sst[0];
    int span   = sst[VPB] - bstart;
    bool fits  = (span <= IDX_CAP);
    if (fits) {
        for (int i = threadIdx.x; i < span; i += 256)
            sidx[i] = sorted_idx[bstart + i];
    }
    __syncthreads();

    int g   = threadIdx.x >> 4;       // voxel within block 0..15
    int sub = threadIdx.x & 15;       // channel quad
    int s0  = sst[g];
    int cnt = sst[g + 1] - s0;
    float4* outp = &out4[(size_t)(vox0 + g) * 16 + sub];

    if (cnt == 0) {
        ntstore4(outp, make_float4(0.f, 0.f, 0.f, 0.f));
        return;
    }

    int off = s0 - bstart;
    float4 a0 = make_float4(-INFINITY, -INFINITY, -INFINITY, -INFINITY);
    float4 a1 = a0, a2 = a0, a3 = a0;

    int j = 0;
    for (; j + 4 <= cnt; j += 4) {
        int p0, p1, p2, p3;
        if (fits) {
            p0 = sidx[off + j];     p1 = sidx[off + j + 1];
            p2 = sidx[off + j + 2]; p3 = sidx[off + j + 3];
        } else {
            p0 = sorted_idx[s0 + j];     p1 = sorted_idx[s0 + j + 1];
            p2 = sorted_idx[s0 + j + 2]; p3 = sorted_idx[s0 + j + 3];
        }
        a0 = max4(a0, ntload4(&feats4[(size_t)p0 * 16 + sub]));
        a1 = max4(a1, ntload4(&feats4[(size_t)p1 * 16 + sub]));
        a2 = max4(a2, ntload4(&feats4[(size_t)p2 * 16 + sub]));
        a3 = max4(a3, ntload4(&feats4[(size_t)p3 * 16 + sub]));
    }
    for (; j < cnt; j++) {                      // exact scalar tail (<=3)
        int p = fits ? sidx[off + j] : sorted_idx[s0 + j];
        a0 = max4(a0, ntload4(&feats4[(size_t)p * 16 + sub]));
    }
    ntstore4(outp, max4(max4(a0, a1), max4(a2, a3)));
}

// ============================================================================
extern "C" void kernel_launch(void* const* d_in, const int* in_sizes, int n_in,
                              void* d_out, int out_size, void* d_ws, size_t ws_size,
                              hipStream_t stream) {
    const int*   verts = (const int*)d_in[0];    // [N,3] int32
    const float* feats = (const float*)d_in[1];  // [N,64] fp32
    float*       out   = (float*)d_out;          // [N_VOX*64] fp32

    const int n_pts = in_sizes[0] / 3;           // 1,000,000

    char* w = (char*)d_ws;
    int*  vox        = (int*)w;              w += (size_t)n_pts * 4;
    int*  rank       = (int*)w;              w += (size_t)n_pts * 4;
    int*  sorted_idx = (int*)w;              w += (size_t)n_pts * 4;
    // --- zeroed region: counts | state | ticket (one memset) ---
    int*  counts     = (int*)w;              w += (size_t)N_VOX * 4;
    unsigned long long* state = (unsigned long long*)w;  w += (size_t)NCHUNK * 8;
    int*  ticket     = (int*)w;              w += 16;
    const size_t zero_bytes = (size_t)N_VOX * 4 + (size_t)NCHUNK * 8 + 16;
    // --- end zeroed region ---
    int*  gstart     = (int*)w;              w += (size_t)(N_VOX + 4) * 4;

    hipMemsetAsync(counts, 0, zero_bytes, stream);

    {   // histogram + voxel ids + in-voxel ranks (8 points/thread)
        const int block = 256;
        const int nthr  = (n_pts + 7) / 8;
        const int grid  = (nthr + block - 1) / block;
        k_hist<<<grid, block, 0, stream>>>(verts, vox, rank, counts, n_pts);
    }
    // full exclusive scan -> gstart[N_VOX+1], single kernel
    k_scan<<<NCHUNK, 256, 0, stream>>>(counts, gstart, state, ticket);

    {   // scatter indices, atomic-free (8 points/thread)
        const int block = 256;
        const int nthr  = (n_pts + 7) / 8;
        const int grid  = (nthr + block - 1) / block;
        k_scatter_idx<<<grid, block, 0, stream>>>(vox, rank, gstart,
                                                  sorted_idx, n_pts);
    }
    {   // gather max: 16 voxels per block, LDS-staged indices, exact loads
        const int block = 256;
        const int grid  = N_VOX / VPB;     // 16384
        k_gather<<<grid, block, 0, stream>>>(sorted_idx, gstart,
                                             (const float4*)feats, (float4*)out);
    }
}